// Round 1
// baseline (1745.553 us; speedup 1.0000x reference)
//
#include <hip/hip_runtime.h>
#include <hip/hip_bf16.h>

#define B_SZ 32
#define S_SZ 4096
#define K_SZ 1024
#define H_SZ 1024

typedef __bf16 bf16_8 __attribute__((ext_vector_type(8)));
typedef __bf16 bf16_4 __attribute__((ext_vector_type(4)));
typedef float f32x4 __attribute__((ext_vector_type(4)));

__device__ inline bf16_8 cvt8(f32x4 a, f32x4 b) {
    bf16_8 o;
    o[0] = (__bf16)a[0]; o[1] = (__bf16)a[1]; o[2] = (__bf16)a[2]; o[3] = (__bf16)a[3];
    o[4] = (__bf16)b[0]; o[5] = (__bf16)b[1]; o[6] = (__bf16)b[2]; o[7] = (__bf16)b[3];
    return o;
}

// ---------------- zero scores + context accumulators ----------------
__global__ void zero_kernel(float* __restrict__ scores, float* __restrict__ ctx) {
    int i = blockIdx.x * 256 + threadIdx.x;
    if (i < B_SZ * S_SZ) scores[i] = 0.f;
    if (i < B_SZ * H_SZ) ctx[i] = 0.f;
}

// ---------------- q_proj + Wq_b + Wk_b -> qb [B,H] ----------------
__global__ __launch_bounds__(256) void qproj_kernel(
    const float* __restrict__ query, const float* __restrict__ Wq,
    const float* __restrict__ Wq_b, const float* __restrict__ Wk_b,
    float* __restrict__ qb)
{
    __shared__ float qs[K_SZ];
    const int b = blockIdx.x;
    const int h = blockIdx.y * 256 + threadIdx.x;
    for (int k = threadIdx.x; k < K_SZ; k += 256) qs[k] = query[b * K_SZ + k];
    __syncthreads();
    const float* w = Wq + (size_t)h * K_SZ;
    float acc = 0.f;
    #pragma unroll 4
    for (int k = 0; k < K_SZ; k += 4) {
        f32x4 wv = *reinterpret_cast<const f32x4*>(w + k);
        acc += wv[0]*qs[k] + wv[1]*qs[k+1] + wv[2]*qs[k+2] + wv[3]*qs[k+3];
    }
    qb[b * H_SZ + h] = acc + Wq_b[h] + Wk_b[h];
}

// ---------------- Wk fp32 -> bf16 ----------------
__global__ void cvt_wk_kernel(const float* __restrict__ Wk, __bf16* __restrict__ WkB) {
    int i = (blockIdx.x * 256 + threadIdx.x) * 4;
    f32x4 f = *reinterpret_cast<const f32x4*>(Wk + i);
    bf16_4 h;
    h[0] = (__bf16)f[0]; h[1] = (__bf16)f[1]; h[2] = (__bf16)f[2]; h[3] = (__bf16)f[3];
    *reinterpret_cast<bf16_4*>(WkB + i) = h;
}

// ---------------- fused k_proj GEMM + tanh + dot(v_w) -> scores ----------------
// grid: x = h-tile (8), y = tile_m (1024). block = 256 (4 waves, 2x2 of 64x64).
__global__ __launch_bounds__(256) void gemm_scores_kernel(
    const float* __restrict__ keys,   // [B,S,K] fp32
    const __bf16* __restrict__ WkB,   // [H,K] bf16
    const float* __restrict__ qb,     // [B,H]
    const float* __restrict__ vw,     // [H]
    float* __restrict__ scores)       // [B,S] atomic accum
{
    __shared__ alignas(16) __bf16 Als[128][40]; // +8 pad: breaks 64B-stride bank conflicts
    __shared__ alignas(16) __bf16 Bls[128][40];

    const int tid  = threadIdx.x;
    const int wave = tid >> 6;
    const int lane = tid & 63;
    const int quad = lane >> 4;
    const int l15  = lane & 15;
    const int wm   = wave >> 1;   // 0..1  (M half)
    const int wn   = wave & 1;    // 0..1  (N half)

    const int n0     = blockIdx.x * 128;   // h-tile start
    const int tile_m = blockIdx.y;
    const int b      = tile_m >> 5;
    const int s0     = (tile_m & 31) * 128;

    const float* Ag = keys + ((size_t)b * S_SZ + s0) * K_SZ;

    const int srow  = tid >> 1;        // 0..127
    const int skoff = (tid & 1) * 16;  // 0 or 16

    f32x4 acc[4][4];
    #pragma unroll
    for (int i = 0; i < 4; i++)
        #pragma unroll
        for (int j = 0; j < 4; j++) acc[i][j] = f32x4{0.f, 0.f, 0.f, 0.f};

    for (int kk = 0; kk < K_SZ; kk += 32) {
        // stage A (fp32 keys -> bf16 LDS): 128 rows x 32 k
        const float* asrc = Ag + (size_t)srow * K_SZ + kk + skoff;
        const __bf16* bsrc = WkB + (size_t)(n0 + srow) * K_SZ + kk + skoff;
        #pragma unroll
        for (int g = 0; g < 2; ++g) {
            f32x4 f0 = *reinterpret_cast<const f32x4*>(asrc + g * 8);
            f32x4 f1 = *reinterpret_cast<const f32x4*>(asrc + g * 8 + 4);
            *reinterpret_cast<bf16_8*>(&Als[srow][skoff + g * 8]) = cvt8(f0, f1);
            *reinterpret_cast<bf16_8*>(&Bls[srow][skoff + g * 8]) =
                *reinterpret_cast<const bf16_8*>(bsrc + g * 8);
        }
        __syncthreads();

        bf16_8 aF[4], bF[4];
        #pragma unroll
        for (int i = 0; i < 4; i++)
            aF[i] = *reinterpret_cast<const bf16_8*>(&Als[wm * 64 + i * 16 + l15][quad * 8]);
        #pragma unroll
        for (int j = 0; j < 4; j++)
            bF[j] = *reinterpret_cast<const bf16_8*>(&Bls[wn * 64 + j * 16 + l15][quad * 8]);
        #pragma unroll
        for (int i = 0; i < 4; i++)
            #pragma unroll
            for (int j = 0; j < 4; j++)
                acc[i][j] = __builtin_amdgcn_mfma_f32_16x16x32_bf16(aF[i], bF[j], acc[i][j], 0, 0, 0);
        __syncthreads();
    }

    // epilogue: score_partial[m] = sum_n vw[h] * tanh(acc + qb[b,h])
    const int hbase = n0 + wn * 64 + l15;
    float vws[4], qbs[4];
    #pragma unroll
    for (int j = 0; j < 4; j++) {
        vws[j] = vw[hbase + j * 16];
        qbs[j] = qb[b * H_SZ + hbase + j * 16];
    }
    float part[16];
    #pragma unroll
    for (int i = 0; i < 4; i++)
        #pragma unroll
        for (int r = 0; r < 4; r++) {
            float p = 0.f;
            #pragma unroll
            for (int j = 0; j < 4; j++)
                p += vws[j] * tanhf(acc[i][j][r] + qbs[j]);
            part[i * 4 + r] = p;
        }
    // butterfly over the 16 lanes sharing the same M rows (same quad)
    #pragma unroll
    for (int t = 0; t < 16; t++) {
        #pragma unroll
        for (int off = 8; off >= 1; off >>= 1)
            part[t] += __shfl_xor(part[t], off, 16);
    }
    if (l15 == 0) {
        float* sc = scores + (size_t)b * S_SZ + s0 + wm * 64 + quad * 4;
        #pragma unroll
        for (int i = 0; i < 4; i++)
            #pragma unroll
            for (int r = 0; r < 4; r++)
                atomicAdd(&sc[i * 16 + r], part[i * 4 + r]);
    }
}

// ---------------- masked softmax over S ----------------
__global__ __launch_bounds__(256) void softmax_kernel(
    const float* __restrict__ scores, const int* __restrict__ mask,
    float* __restrict__ wout)
{
    const int b = blockIdx.x;
    const int tid = threadIdx.x;
    float v[16];
    float mx = -INFINITY;
    #pragma unroll
    for (int t = 0; t < 16; t++) {
        int s = tid + t * 256;
        float sc = scores[b * S_SZ + s];
        v[t] = (mask[b * S_SZ + s] == 0) ? -INFINITY : sc;
        mx = fmaxf(mx, v[t]);
    }
    #pragma unroll
    for (int off = 32; off >= 1; off >>= 1) mx = fmaxf(mx, __shfl_xor(mx, off, 64));
    __shared__ float wred[4];
    if ((tid & 63) == 0) wred[tid >> 6] = mx;
    __syncthreads();
    mx = fmaxf(fmaxf(wred[0], wred[1]), fmaxf(wred[2], wred[3]));

    float sum = 0.f;
    #pragma unroll
    for (int t = 0; t < 16; t++) { v[t] = __expf(v[t] - mx); sum += v[t]; }
    #pragma unroll
    for (int off = 32; off >= 1; off >>= 1) sum += __shfl_xor(sum, off, 64);
    __shared__ float sred[4];
    if ((tid & 63) == 0) sred[tid >> 6] = sum;
    __syncthreads();
    sum = sred[0] + sred[1] + sred[2] + sred[3];
    float inv = 1.f / sum;
    #pragma unroll
    for (int t = 0; t < 16; t++) wout[b * S_SZ + tid + t * 256] = v[t] * inv;
}

// ---------------- context = sum_s w[b,s] * values[b,s,:] ----------------
// grid: (16 s-chunks, 32 b), block 256: thread t owns d = 4t (float4)
__global__ __launch_bounds__(256) void context_kernel(
    const float* __restrict__ values, const float* __restrict__ w,
    float* __restrict__ ctx)
{
    const int chunk = blockIdx.x;
    const int b = blockIdx.y;
    const int s0 = chunk * 256;
    __shared__ float wsm[256];
    wsm[threadIdx.x] = w[b * S_SZ + s0 + threadIdx.x];
    __syncthreads();
    const int d = threadIdx.x * 4;
    const float4* vp = reinterpret_cast<const float4*>(
        values + ((size_t)b * S_SZ + s0) * K_SZ + d);
    float4 acc = {0.f, 0.f, 0.f, 0.f};
    #pragma unroll 4
    for (int s = 0; s < 256; ++s) {
        float4 vv = vp[(size_t)s * (K_SZ / 4)];
        float ws_ = wsm[s];
        acc.x += ws_ * vv.x; acc.y += ws_ * vv.y;
        acc.z += ws_ * vv.z; acc.w += ws_ * vv.w;
    }
    atomicAdd(&ctx[b * H_SZ + d + 0], acc.x);
    atomicAdd(&ctx[b * H_SZ + d + 1], acc.y);
    atomicAdd(&ctx[b * H_SZ + d + 2], acc.z);
    atomicAdd(&ctx[b * H_SZ + d + 3], acc.w);
}

extern "C" void kernel_launch(void* const* d_in, const int* in_sizes, int n_in,
                              void* d_out, int out_size, void* d_ws, size_t ws_size,
                              hipStream_t stream) {
    const float* query  = (const float*)d_in[0];
    const float* keys   = (const float*)d_in[1];
    const float* values = (const float*)d_in[2];
    const int*   mask   = (const int*)d_in[3];
    const float* Wq_w   = (const float*)d_in[4];
    const float* Wq_b   = (const float*)d_in[5];
    const float* Wk_w   = (const float*)d_in[6];
    const float* Wk_b   = (const float*)d_in[7];
    const float* v_w    = (const float*)d_in[8];

    float* ctx_out = (float*)d_out;                 // [32,1024]
    float* w_out   = (float*)d_out + B_SZ * H_SZ;   // [32,4096]

    char* ws = (char*)d_ws;
    float*  qb     = (float*)ws;                              // 128 KB
    __bf16* WkB    = (__bf16*)(ws + (128 << 10));             // 2 MB
    float*  scores = (float*)(ws + (128 << 10) + (2 << 20));  // 512 KB

    zero_kernel<<<512, 256, 0, stream>>>(scores, ctx_out);
    qproj_kernel<<<dim3(32, 4), 256, 0, stream>>>(query, Wq_w, Wq_b, Wk_b, qb);
    cvt_wk_kernel<<<1024, 256, 0, stream>>>(Wk_w, WkB);
    gemm_scores_kernel<<<dim3(8, 1024), 256, 0, stream>>>(keys, WkB, qb, v_w, scores);
    softmax_kernel<<<32, 256, 0, stream>>>(scores, mask, w_out);
    context_kernel<<<dim3(16, 32), 256, 0, stream>>>(values, w_out, ctx_out);
}